// Round 1
// baseline (2213.356 us; speedup 1.0000x reference)
//
#include <hip/hip_runtime.h>
#include <hip/hip_bf16.h>
#include <stdint.h>

typedef __bf16 bf16_t;
typedef __bf16 bf16x8 __attribute__((ext_vector_type(8)));
typedef float f32x4 __attribute__((ext_vector_type(4)));

#define AS1(p) ((const __attribute__((address_space(1))) void*)(uintptr_t)(p))
#define AS3(p) ((__attribute__((address_space(3))) void*)(uintptr_t)(p))

__device__ __forceinline__ void gload16(const bf16_t* g, bf16_t* l) {
  // 16B direct global->LDS (dest = wave-uniform base + lane*16; our layout is exactly linear)
  __builtin_amdgcn_global_load_lds(AS1(g), AS3(l), 16, 0, 0);
}

// ---------------- shared 128x128 B^T-form GEMM core ----------------
// C[row][col] = sum_k A[row][k] * B[col][k], 256 threads, 4 waves (2x2 of 64x64),
// BK=32, mfma_f32_16x16x32_bf16, 4x4 fragments per wave. kdim % 32 == 0.
__device__ __forceinline__ void gemm_bt_core(const bf16_t* __restrict__ A, int lda,
                                             const bf16_t* __restrict__ B, int ldb,
                                             int kdim, f32x4 acc[4][4],
                                             bf16_t* As, bf16_t* Bs) {
  const int t = threadIdx.x;
  const int lane = t & 63, wave = t >> 6;
  const int wr = wave >> 1, wc = wave & 1;
  const int fr = lane & 15, fq = lane >> 4;

  const bf16_t* ga0 = A + (size_t)(t >> 2) * lda + (t & 3) * 8;
  const bf16_t* ga1 = ga0 + (size_t)64 * lda;
  const bf16_t* gb0 = B + (size_t)(t >> 2) * ldb + (t & 3) * 8;
  const bf16_t* gb1 = gb0 + (size_t)64 * ldb;
  bf16_t* la0 = As + t * 8;
  bf16_t* la1 = As + 2048 + t * 8;
  bf16_t* lb0 = Bs + t * 8;
  bf16_t* lb1 = Bs + 2048 + t * 8;
  const bf16_t* fa = As + (wr * 64 + fr) * 32 + fq * 8;
  const bf16_t* fb = Bs + (wc * 64 + fr) * 32 + fq * 8;

  for (int k0 = 0; k0 < kdim; k0 += 32) {
    gload16(ga0, la0);
    gload16(ga1, la1);
    gload16(gb0, lb0);
    gload16(gb1, lb1);
    ga0 += 32; ga1 += 32; gb0 += 32; gb1 += 32;
    asm volatile("s_waitcnt vmcnt(0)" ::: "memory");
    __syncthreads();
    bf16x8 af[4], bfr[4];
#pragma unroll
    for (int i = 0; i < 4; ++i) af[i] = *(const bf16x8*)(fa + i * 512);
#pragma unroll
    for (int i = 0; i < 4; ++i) bfr[i] = *(const bf16x8*)(fb + i * 512);
#pragma unroll
    for (int mi = 0; mi < 4; ++mi)
#pragma unroll
      for (int ni = 0; ni < 4; ++ni)
        acc[mi][ni] = __builtin_amdgcn_mfma_f32_16x16x32_bf16(af[mi], bfr[ni], acc[mi][ni], 0, 0, 0);
    __syncthreads();
  }
}

#define ZERO_ACC(acc)                         \
  f32x4 _z = {0.f, 0.f, 0.f, 0.f};            \
  _Pragma("unroll") for (int _i = 0; _i < 4; ++_i) \
  _Pragma("unroll") for (int _j = 0; _j < 4; ++_j) acc[_i][_j] = _z;

// ---------------- conversions ----------------
__global__ void k_cvt(const float* __restrict__ s, bf16_t* __restrict__ d, long n8) {
  long i = (long)blockIdx.x * blockDim.x + threadIdx.x;
  long st = (long)gridDim.x * blockDim.x;
  for (; i < n8; i += st) {
    const float4* sp = (const float4*)(s + i * 8);
    float4 a = sp[0], b = sp[1];
    bf16x8 v;
    v[0] = (__bf16)a.x; v[1] = (__bf16)a.y; v[2] = (__bf16)a.z; v[3] = (__bf16)a.w;
    v[4] = (__bf16)b.x; v[5] = (__bf16)b.y; v[6] = (__bf16)b.z; v[7] = (__bf16)b.w;
    *(bf16x8*)(d + i * 8) = v;
  }
}

__global__ void k_fill(float* o, float v, long n) {
  long i = (long)blockIdx.x * blockDim.x + threadIdx.x;
  long st = (long)gridDim.x * blockDim.x;
  for (; i < n; i += st) o[i] = v;
}

// ---------------- GEMM 1: QKV projection ----------------
// xb: (32768, 2048) bf16. Wb: (6144, 2048) bf16 = [Wq;Wk;Wv] flat.
// nt<32: C = x*W^T -> Q/K at (pair, t, d). nt>=32: operands swapped (C = W*x^T) -> V
// stored transposed Vt at (pair, d, t) with coalesced stores.
__global__ __launch_bounds__(256) void k_gemm_qkv(
    const bf16_t* __restrict__ xb, const bf16_t* __restrict__ Wb,
    const float* __restrict__ bq, const float* __restrict__ bk, const float* __restrict__ bv,
    bf16_t* __restrict__ Q, bf16_t* __restrict__ K, bf16_t* __restrict__ Vt) {
  __shared__ bf16_t As[4096], Bs[4096];
  int bid = blockIdx.x;
  int nt = bid % 48, mt = bid / 48;
  const int t = threadIdx.x, lane = t & 63, wave = t >> 6;
  const int wr = wave >> 1, wc = wave & 1, fr = lane & 15, fq = lane >> 4;
  f32x4 acc[4][4];
  ZERO_ACC(acc)

  bool vmode = (nt >= 32);
  const bf16_t* Arows = vmode ? (Wb + (size_t)nt * 128 * 2048) : (xb + (size_t)mt * 128 * 2048);
  const bf16_t* Brows = vmode ? (xb + (size_t)mt * 128 * 2048) : (Wb + (size_t)nt * 128 * 2048);
  gemm_bt_core(Arows, 2048, Brows, 2048, 2048, acc, As, Bs);

  if (!vmode) {
    int sel = nt >> 4;  // 0 -> Q, 1 -> K
    const float* bias = sel ? bk : bq;
    bf16_t* dst = sel ? K : Q;
    int gn0 = (nt & 15) * 128;
#pragma unroll
    for (int mi = 0; mi < 4; ++mi)
#pragma unroll
      for (int ni = 0; ni < 4; ++ni) {
        int col = gn0 + wc * 64 + ni * 16 + fr;  // [0,2048)
        int h = col >> 10, d = col & 1023;
        float bb = bias[col];
        f32x4 a = acc[mi][ni];
#pragma unroll
        for (int r = 0; r < 4; ++r) {
          int m = mt * 128 + wr * 64 + mi * 16 + fq * 4 + r;
          int b = m >> 10, tt = m & 1023;
          dst[(((size_t)(b * 2 + h) << 10) + tt) * 1024 + d] = (bf16_t)(a[r] + bb);
        }
      }
  } else {
#pragma unroll
    for (int mi = 0; mi < 4; ++mi)
#pragma unroll
      for (int ni = 0; ni < 4; ++ni) {
        int m = mt * 128 + wc * 64 + ni * 16 + fr;  // C' cols = token index
        int b = m >> 10, tt = m & 1023;
        f32x4 a = acc[mi][ni];
#pragma unroll
        for (int r = 0; r < 4; ++r) {
          int gd = nt * 128 - 4096 + wr * 64 + mi * 16 + fq * 4 + r;  // [0,2048)
          int h = gd >> 10, d = gd & 1023;
          Vt[(((size_t)(b * 2 + h) << 10) + d) * 1024 + tt] = (bf16_t)(a[r] + bv[gd]);
        }
      }
  }
}

// ---------------- GEMM 2: S = Q K^T * scale (lower-tri tiles only) ----------------
__global__ __launch_bounds__(256) void k_gemm_s(const bf16_t* __restrict__ Q,
                                                const bf16_t* __restrict__ K,
                                                float* __restrict__ S, int pbase) {
  __shared__ bf16_t As[4096], Bs[4096];
  int bid = blockIdx.x;
  int pc = bid / 36, idx = bid % 36;
  int ti = 0;
  while (idx > ti) { idx -= ti + 1; ++ti; }
  int tj = idx;
  size_t p = (size_t)(pbase + pc);
  const int t = threadIdx.x, lane = t & 63, wave = t >> 6;
  const int wr = wave >> 1, wc = wave & 1, fr = lane & 15, fq = lane >> 4;
  f32x4 acc[4][4];
  ZERO_ACC(acc)
  gemm_bt_core(Q + (p << 20) + (size_t)ti * 128 * 1024, 1024,
               K + (p << 20) + (size_t)tj * 128 * 1024, 1024, 1024, acc, As, Bs);
  float* Sp = S + ((size_t)pc << 20);
  const float scale = 0.022097086912079608f;  // 1/sqrt(2048)
#pragma unroll
  for (int mi = 0; mi < 4; ++mi)
#pragma unroll
    for (int ni = 0; ni < 4; ++ni) {
      int col = tj * 128 + wc * 64 + ni * 16 + fr;
      f32x4 a = acc[mi][ni];
#pragma unroll
      for (int r = 0; r < 4; ++r) {
        int row = ti * 128 + wr * 64 + mi * 16 + fq * 4 + r;
        Sp[(size_t)row * 1024 + col] = a[r] * scale;
      }
    }
}

// ---------------- softmax (one block per row, causal) ----------------
__global__ __launch_bounds__(256) void k_softmax(const float* __restrict__ S,
                                                 bf16_t* __restrict__ P) {
  int bid = blockIdx.x;
  int pc = bid >> 10, row = bid & 1023;
  const float* s = S + ((size_t)pc << 20) + (size_t)row * 1024;
  bf16_t* p = P + ((size_t)pc << 20) + (size_t)row * 1024;
  int cend = ((row >> 7) + 1) << 7;
  int t = threadIdx.x;
  __shared__ float red[8];
  float x[4];
  float mx = -1e30f;
#pragma unroll
  for (int j = 0; j < 4; ++j) {
    int c = t + 256 * j;
    x[j] = (c <= row) ? s[c] : -1e30f;
    mx = fmaxf(mx, x[j]);
  }
  for (int o = 32; o > 0; o >>= 1) mx = fmaxf(mx, __shfl_xor(mx, o));
  if (!(t & 63)) red[t >> 6] = mx;
  __syncthreads();
  mx = fmaxf(fmaxf(red[0], red[1]), fmaxf(red[2], red[3]));
  float e[4];
  float sum = 0.f;
#pragma unroll
  for (int j = 0; j < 4; ++j) {
    e[j] = (x[j] > -1e29f) ? __expf(x[j] - mx) : 0.f;
    sum += e[j];
  }
  for (int o = 32; o > 0; o >>= 1) sum += __shfl_xor(sum, o);
  if (!(t & 63)) red[4 + (t >> 6)] = sum;
  __syncthreads();
  sum = red[4] + red[5] + red[6] + red[7];
  float inv = 1.f / sum;
#pragma unroll
  for (int j = 0; j < 4; ++j) {
    int c = t + 256 * j;
    if (c < cend) p[c] = (bf16_t)(e[j] * inv);
  }
}

// ---------------- GEMM 3: O = P * V (V pre-transposed; causal-shortened K) ----------------
__global__ __launch_bounds__(256) void k_gemm_pv(const bf16_t* __restrict__ P,
                                                 const bf16_t* __restrict__ Vt,
                                                 bf16_t* __restrict__ O, int pbase) {
  __shared__ bf16_t As[4096], Bs[4096];
  int bid = blockIdx.x;
  int pc = bid >> 6, rem = bid & 63;
  int ti = rem >> 3, dj = rem & 7;
  size_t p = (size_t)(pbase + pc);
  const int t = threadIdx.x, lane = t & 63, wave = t >> 6;
  const int wr = wave >> 1, wc = wave & 1, fr = lane & 15, fq = lane >> 4;
  f32x4 acc[4][4];
  ZERO_ACC(acc)
  int kdim = (ti + 1) * 128;
  gemm_bt_core(P + ((size_t)pc << 20) + (size_t)ti * 128 * 1024, 1024,
               Vt + (p << 20) + (size_t)dj * 128 * 1024, 1024, kdim, acc, As, Bs);
  int b = (int)(p >> 1), h = (int)(p & 1);
#pragma unroll
  for (int mi = 0; mi < 4; ++mi)
#pragma unroll
    for (int ni = 0; ni < 4; ++ni) {
      int dcol = dj * 128 + wc * 64 + ni * 16 + fr;
      f32x4 a = acc[mi][ni];
#pragma unroll
      for (int r = 0; r < 4; ++r) {
        int tt = ti * 128 + wr * 64 + mi * 16 + fq * 4 + r;
        O[(((size_t)b << 10) + tt) * 2048 + (h << 10) + dcol] = (bf16_t)a[r];
      }
    }
}

// ---------------- GEMM 4: out = O * Wo^T (fp32 out) ----------------
__global__ __launch_bounds__(256) void k_gemm_out(const bf16_t* __restrict__ O,
                                                  const bf16_t* __restrict__ W,
                                                  float* __restrict__ out) {
  __shared__ bf16_t As[4096], Bs[4096];
  int bid = blockIdx.x;
  int nt = bid & 15, mt = bid >> 4;
  const int t = threadIdx.x, lane = t & 63, wave = t >> 6;
  const int wr = wave >> 1, wc = wave & 1, fr = lane & 15, fq = lane >> 4;
  f32x4 acc[4][4];
  ZERO_ACC(acc)
  gemm_bt_core(O + (size_t)mt * 128 * 2048, 2048, W + (size_t)nt * 128 * 2048, 2048, 2048, acc,
               As, Bs);
#pragma unroll
  for (int mi = 0; mi < 4; ++mi)
#pragma unroll
    for (int ni = 0; ni < 4; ++ni) {
      int col = nt * 128 + wc * 64 + ni * 16 + fr;
      f32x4 a = acc[mi][ni];
#pragma unroll
      for (int r = 0; r < 4; ++r) {
        int row = mt * 128 + wr * 64 + mi * 16 + fq * 4 + r;
        out[(size_t)row * 2048 + col] = a[r];
      }
    }
}

// ---------------- launch ----------------
extern "C" void kernel_launch(void* const* d_in, const int* in_sizes, int n_in,
                              void* d_out, int out_size, void* d_ws, size_t ws_size,
                              hipStream_t stream) {
  const float* x  = (const float*)d_in[0];
  const float* Wq = (const float*)d_in[1];
  const float* bq = (const float*)d_in[2];
  const float* Wk = (const float*)d_in[3];
  const float* bk = (const float*)d_in[4];
  const float* Wv = (const float*)d_in[5];
  const float* bv = (const float*)d_in[6];
  const float* Wo = (const float*)d_in[7];
  float* out = (float*)d_out;

  const size_t MiB = 1ull << 20;
  char* w = (char*)d_ws;
  bf16_t* xb    = (bf16_t*)w;               // 128 MiB, reused as O after GEMM1
  bf16_t* Ob    = xb;
  bf16_t* Qb    = (bf16_t*)(w + 128 * MiB); // 128 MiB
  bf16_t* Kb    = (bf16_t*)(w + 256 * MiB); // 128 MiB
  bf16_t* Vt    = (bf16_t*)(w + 384 * MiB); // 128 MiB (transposed V)
  bf16_t* Wqkvb = (bf16_t*)(w + 512 * MiB); // 24 MiB
  bf16_t* Wob   = (bf16_t*)(w + 536 * MiB); // 8 MiB
  float*  Sc    = (float*)(w + 544 * MiB);  // NP * 4 MiB

  size_t rem = ws_size > 544 * MiB ? ws_size - 544 * MiB : 0;
  int NP = (int)(rem / (6 * MiB));
  if (NP > 64) NP = 64;
  if (NP < 1) {
    // insufficient workspace: encode ws_size (MiB) into output as a diagnostic sentinel
    k_fill<<<2048, 256, 0, stream>>>(out, (float)(ws_size >> 20), (long)out_size);
    return;
  }
  bf16_t* Pc = (bf16_t*)(w + 544 * MiB + (size_t)NP * 4 * MiB); // NP * 2 MiB

  // conversions to bf16
  k_cvt<<<2048, 256, 0, stream>>>(x, xb, 8388608L);
  k_cvt<<<1024, 256, 0, stream>>>(Wq, Wqkvb, 524288L);
  k_cvt<<<1024, 256, 0, stream>>>(Wk, Wqkvb + 4194304, 524288L);
  k_cvt<<<1024, 256, 0, stream>>>(Wv, Wqkvb + 8388608, 524288L);
  k_cvt<<<1024, 256, 0, stream>>>(Wo, Wob, 524288L);

  // QKV projection (Q,K normal layout; V transposed)
  k_gemm_qkv<<<12288, 256, 0, stream>>>(xb, Wqkvb, bq, bk, bv, Qb, Kb, Vt);

  // attention, chunked over (b,h) pairs to bound scratch
  for (int base = 0; base < 64; base += NP) {
    int np = (64 - base) < NP ? (64 - base) : NP;
    k_gemm_s<<<np * 36, 256, 0, stream>>>(Qb, Kb, Sc, base);
    k_softmax<<<np * 1024, 256, 0, stream>>>(Sc, Pc);
    k_gemm_pv<<<np * 64, 256, 0, stream>>>(Pc, Vt, Ob, base);
  }

  // output projection
  k_gemm_out<<<4096, 256, 0, stream>>>(Ob, Wob, out);
}

// Round 3
// 1514.900 us; speedup vs baseline: 1.4611x; 1.4611x over previous
//
#include <hip/hip_runtime.h>
#include <hip/hip_bf16.h>
#include <stdint.h>

typedef __bf16 bf16_t;
typedef __bf16 bf16x8 __attribute__((ext_vector_type(8)));
typedef float f32x4 __attribute__((ext_vector_type(4)));

#define AS1(p) ((const __attribute__((address_space(1))) void*)(uintptr_t)(p))
#define AS3(p) ((__attribute__((address_space(3))) void*)(uintptr_t)(p))

__device__ __forceinline__ void gload16(const bf16_t* g, bf16_t* l) {
  __builtin_amdgcn_global_load_lds(AS1(g), AS3(l), 16, 0, 0);
}

#define BAR()    { __builtin_amdgcn_s_barrier(); __builtin_amdgcn_sched_barrier(0); }
#define VMCNT0() { asm volatile("s_waitcnt vmcnt(0)" ::: "memory"); __builtin_amdgcn_sched_barrier(0); }
#define LGKM0()  { asm volatile("s_waitcnt lgkmcnt(0)" ::: "memory"); __builtin_amdgcn_sched_barrier(0); }

// ================= 256x256 GEMM core (B^T form), race-free drain-0 =================
// C[m][n] = sum_k A[m][k]*B[n][k]. 512 threads = 8 waves (2M x 4N), per-wave 128x64.
// BK=64 as 2 k-halves; LDS per buf: A kh0|A kh1|B kh0|B kh1, 16KB each; 2 bufs = 128KiB.
// Half layout [256 rows][32 k] bf16 with XOR swizzle byte^=((byte>>7)&7)<<4:
//  - write side: LDS dest linear (lane*16), global SOURCE pre-swizzled (rule 21)
//  - read side: same XOR on frag base -> 8-way ds_read_b128 conflict eliminated.
// Sync: prefetch tile t+1 issued at top of tile t; ONE vmcnt(0)+barrier per tile.
// Correct under any completion order / compiler-inserted vmem (no counted vmcnt).
__device__ __forceinline__ void gemm256(const bf16_t* __restrict__ A, int lda,
                                        const bf16_t* __restrict__ B, int ldb,
                                        int nt, f32x4 acc[8][4], bf16_t* lds) {
  const int t = (int)threadIdx.x;
  const int lane = t & 63, w = t >> 6;
  const int wr = w >> 2, wc = w & 3;
  const int fr = lane & 15, fq = lane >> 4;
  char* ldsb = (char*)lds;

  // staging: thread t writes LDS bytes [t*16,+16) (linear); source pre-swizzled
  const int o = t * 16;
  const int s = o ^ (((t >> 3) & 7) << 4);
  const int r0 = s >> 6, q0 = (s >> 4) & 3;
  const bf16_t* gA0 = A + (size_t)r0 * lda + q0 * 8;
  const bf16_t* gA1 = gA0 + (size_t)128 * lda;
  const bf16_t* gB0 = B + (size_t)r0 * ldb + q0 * 8;
  const bf16_t* gB1 = gB0 + (size_t)128 * ldb;

  // frag read bases (bytes within a 16KB half), same XOR (bits[9:7] = fr>>1 always)
  const int x = ((fr >> 1) & 7) << 4;
  const int abase = wr * 8192 + ((fr * 64 + fq * 16) ^ x);
  const int bbase = wc * 4096 + ((fr * 64 + fq * 16) ^ x);

  bf16x8 af[4], bvv[4];

#define STAGE_A(cb, kh, kof) \
  gload16(gA0 + (kof) + (kh) * 32, lds + (cb) * 32768 + (kh) * 8192 + t * 8); \
  gload16(gA1 + (kof) + (kh) * 32, lds + (cb) * 32768 + (kh) * 8192 + 4096 + t * 8);
#define STAGE_B(cb, kh, kof) \
  gload16(gB0 + (kof) + (kh) * 32, lds + (cb) * 32768 + 16384 + (kh) * 8192 + t * 8); \
  gload16(gB1 + (kof) + (kh) * 32, lds + (cb) * 32768 + 16384 + (kh) * 8192 + 4096 + t * 8);
#define DS_LOAD(cb, kh, qm) \
  { const char* ap = ldsb + (cb) * 65536 + (kh) * 16384 + abase + (qm) * 4096; \
    const char* bp = ldsb + (cb) * 65536 + 32768 + (kh) * 16384 + bbase; \
    _Pragma("unroll") for (int i = 0; i < 4; ++i) af[i] = *(const bf16x8*)(ap + i * 1024); \
    _Pragma("unroll") for (int n = 0; n < 4; ++n) bvv[n] = *(const bf16x8*)(bp + n * 1024); }
#define MFMA16(qm) \
  { __builtin_amdgcn_s_setprio(1); \
    _Pragma("unroll") for (int i = 0; i < 4; ++i) \
      _Pragma("unroll") for (int n = 0; n < 4; ++n) \
        acc[(qm) * 4 + i][n] = __builtin_amdgcn_mfma_f32_16x16x32_bf16(af[i], bvv[n], acc[(qm) * 4 + i][n], 0, 0, 0); \
    __builtin_amdgcn_s_setprio(0); }

  // prologue: stage tile 0 into buf0, drain, barrier
  STAGE_A(0, 0, 0) STAGE_B(0, 0, 0) STAGE_A(0, 1, 0) STAGE_B(0, 1, 0)
  VMCNT0() BAR()

  int kof = 64;
  for (int tt = 0; tt < nt - 1; ++tt, kof += 64) {
    const int cb = tt & 1;
    // issue ALL of tile t+1's prefetch early; compute current tile in 4 sub-phases
    DS_LOAD(cb, 0, 0) STAGE_A(cb ^ 1, 0, kof) STAGE_A(cb ^ 1, 1, kof) LGKM0() MFMA16(0)
    DS_LOAD(cb, 0, 1) STAGE_B(cb ^ 1, 0, kof) STAGE_B(cb ^ 1, 1, kof) LGKM0() MFMA16(1)
    DS_LOAD(cb, 1, 0) LGKM0() MFMA16(0)
    DS_LOAD(cb, 1, 1) LGKM0() MFMA16(1)
    VMCNT0() BAR()   // all writes to buf cb^1 landed; all reads of buf cb drained (lgkm0s)
  }
  {  // tail tile: reads only
    const int cb = (nt - 1) & 1;
    DS_LOAD(cb, 0, 0) LGKM0() MFMA16(0)
    DS_LOAD(cb, 0, 1) LGKM0() MFMA16(1)
    DS_LOAD(cb, 1, 0) LGKM0() MFMA16(0)
    DS_LOAD(cb, 1, 1) LGKM0() MFMA16(1)
  }
#undef STAGE_A
#undef STAGE_B
#undef DS_LOAD
#undef MFMA16
}

#define EPI_VARS \
  const int t = (int)threadIdx.x; \
  const int lane = t & 63, w = t >> 6; \
  const int wr = w >> 2, wc = w & 3; \
  const int fr = lane & 15, fq = lane >> 4;

#define ZERO8x4(acc) \
  _Pragma("unroll") for (int _i = 0; _i < 8; ++_i) \
  _Pragma("unroll") for (int _j = 0; _j < 4; ++_j) { f32x4 _z = {0.f,0.f,0.f,0.f}; acc[_i][_j] = _z; }

// ---------------- conversions ----------------
__global__ void k_cvt(const float* __restrict__ s, bf16_t* __restrict__ d, long n8) {
  long i = (long)blockIdx.x * blockDim.x + threadIdx.x;
  long st = (long)gridDim.x * blockDim.x;
  for (; i < n8; i += st) {
    const float4* sp = (const float4*)(s + i * 8);
    float4 a = sp[0], b = sp[1];
    bf16x8 v;
    v[0] = (__bf16)a.x; v[1] = (__bf16)a.y; v[2] = (__bf16)a.z; v[3] = (__bf16)a.w;
    v[4] = (__bf16)b.x; v[5] = (__bf16)b.y; v[6] = (__bf16)b.z; v[7] = (__bf16)b.w;
    *(bf16x8*)(d + i * 8) = v;
  }
}

__global__ void k_fill(float* o, float v, long n) {
  long i = (long)blockIdx.x * blockDim.x + threadIdx.x;
  long st = (long)gridDim.x * blockDim.x;
  for (; i < n; i += st) o[i] = v;
}

// ---------------- GEMM 1: QKV projection (256-tile) ----------------
__global__ __launch_bounds__(512, 2) void k_qkv256(
    const bf16_t* __restrict__ xb, const bf16_t* __restrict__ Wb,
    const float* __restrict__ bq, const float* __restrict__ bk, const float* __restrict__ bv,
    bf16_t* __restrict__ Q, bf16_t* __restrict__ K, bf16_t* __restrict__ Vt) {
  __shared__ __align__(16) bf16_t lds[65536];
  int bid = (int)blockIdx.x;
  int id = (bid & 7) * 384 + (bid >> 3);  // XCD-bijective swizzle (3072 = 8*384)
  EPI_VARS
  f32x4 acc[8][4];
  ZERO8x4(acc)

  bool vmode = id >= 2048;
  int mt = 0, ntile = 0, tok = 0, wm = 0;
  const bf16_t *Ap, *Bp;
  if (!vmode) {
    mt = id & 127; ntile = id >> 7;  // B-panel-major: resident blocks share W panel
    Ap = xb + (size_t)mt * 256 * 2048;
    Bp = Wb + (size_t)ntile * 256 * 2048;
  } else {
    int vb = id - 2048;
    tok = vb & 127; wm = vb >> 7;
    Ap = Wb + (size_t)(16 + wm) * 256 * 2048;
    Bp = xb + (size_t)tok * 256 * 2048;
  }
  gemm256(Ap, 2048, Bp, 2048, 32, acc, lds);

  if (!vmode) {
    int sel = ntile >> 3;  // 0 -> Q, 1 -> K
    const float* bias = sel ? bk : bq;
    bf16_t* dst = sel ? K : Q;
    int cbase = (ntile & 7) * 256 + wc * 64;
#pragma unroll
    for (int ni = 0; ni < 4; ++ni) {
      int c2 = cbase + ni * 16 + fr;  // [0,2048)
      int h = c2 >> 10, d = c2 & 1023;
      float bb = bias[c2];
#pragma unroll
      for (int mi = 0; mi < 8; ++mi) {
        f32x4 a = acc[mi][ni];
#pragma unroll
        for (int r = 0; r < 4; ++r) {
          int m = mt * 256 + wr * 128 + mi * 16 + fq * 4 + r;
          int b = m >> 10, tk = m & 1023;
          dst[(((size_t)(b * 2 + h) << 10) + tk) * 1024 + d] = (bf16_t)(a[r] + bb);
        }
      }
    }
  } else {
#pragma unroll
    for (int mi = 0; mi < 8; ++mi) {
#pragma unroll
      for (int r = 0; r < 4; ++r) {
        int gd = wm * 256 + wr * 128 + mi * 16 + fq * 4 + r;  // [0,2048)
        int h = gd >> 10, d = gd & 1023;
        float bb = bv[gd];
#pragma unroll
        for (int ni = 0; ni < 4; ++ni) {
          int m = tok * 256 + wc * 64 + ni * 16 + fr;
          int b = m >> 10, tk = m & 1023;
          Vt[(((size_t)(b * 2 + h) << 10) + d) * 1024 + tk] = (bf16_t)(acc[mi][ni][r] + bb);
        }
      }
    }
  }
}

// ---------------- GEMM 2: S = Q K^T * scale (lower-tri 256-tiles) ----------------
__global__ __launch_bounds__(512, 2) void k_s256(const bf16_t* __restrict__ Q,
                                                 const bf16_t* __restrict__ K,
                                                 float* __restrict__ S, int pbase) {
  __shared__ __align__(16) bf16_t lds[65536];
  int id = (int)blockIdx.x;
  int pc = id / 10, rem = id % 10;
  int ti = 0;
  while (rem > ti) { rem -= ti + 1; ++ti; }
  int tj = rem;
  size_t p = (size_t)(pbase + pc);
  EPI_VARS
  f32x4 acc[8][4];
  ZERO8x4(acc)
  gemm256(Q + (p << 20) + (size_t)ti * 256 * 1024, 1024,
          K + (p << 20) + (size_t)tj * 256 * 1024, 1024, 16, acc, lds);
  float* Sp = S + ((size_t)pc << 20);
  const float scale = 0.022097086912079608f;  // 1/sqrt(2048)
#pragma unroll
  for (int mi = 0; mi < 8; ++mi)
#pragma unroll
    for (int ni = 0; ni < 4; ++ni) {
      int col = tj * 256 + wc * 64 + ni * 16 + fr;
      f32x4 a = acc[mi][ni];
#pragma unroll
      for (int r = 0; r < 4; ++r) {
        int row = ti * 256 + wr * 128 + mi * 16 + fq * 4 + r;
        Sp[((size_t)row << 10) + col] = a[r] * scale;
      }
    }
}

// ---------------- softmax (one block per row, causal); zero-fills to 256-aligned end
__global__ __launch_bounds__(256) void k_softmax(const float* __restrict__ S,
                                                 bf16_t* __restrict__ P) {
  int bid = blockIdx.x;
  int pc = bid >> 10, row = bid & 1023;
  const float* s = S + ((size_t)pc << 20) + ((size_t)row << 10);
  bf16_t* p = P + ((size_t)pc << 20) + ((size_t)row << 10);
  int cend = ((row >> 8) + 1) << 8;  // 256-aligned (PV K-tile width)
  int t = threadIdx.x;
  __shared__ float red[8];
  float x[4];
  float mx = -1e30f;
#pragma unroll
  for (int j = 0; j < 4; ++j) {
    int c = t + 256 * j;
    x[j] = (c <= row) ? s[c] : -1e30f;
    mx = fmaxf(mx, x[j]);
  }
  for (int o = 32; o > 0; o >>= 1) mx = fmaxf(mx, __shfl_xor(mx, o));
  if (!(t & 63)) red[t >> 6] = mx;
  __syncthreads();
  mx = fmaxf(fmaxf(red[0], red[1]), fmaxf(red[2], red[3]));
  float e[4];
  float sum = 0.f;
#pragma unroll
  for (int j = 0; j < 4; ++j) {
    e[j] = (x[j] > -1e29f) ? __expf(x[j] - mx) : 0.f;
    sum += e[j];
  }
  for (int o = 32; o > 0; o >>= 1) sum += __shfl_xor(sum, o);
  if (!(t & 63)) red[4 + (t >> 6)] = sum;
  __syncthreads();
  sum = red[4] + red[5] + red[6] + red[7];
  float inv = 1.f / sum;
#pragma unroll
  for (int j = 0; j < 4; ++j) {
    int c = t + 256 * j;
    if (c < cend) p[c] = (bf16_t)(e[j] * inv);
  }
}

// ---------------- GEMM 3: O = P * V (V pre-transposed; causal-shortened K) ----------------
__global__ __launch_bounds__(512, 2) void k_pv256(const bf16_t* __restrict__ P,
                                                  const bf16_t* __restrict__ Vt,
                                                  bf16_t* __restrict__ O, int pbase) {
  __shared__ __align__(16) bf16_t lds[65536];
  int id = (int)blockIdx.x;
  int pc = id >> 4, rem = id & 15;
  int ti = rem >> 2, dj = rem & 3;
  size_t p = (size_t)(pbase + pc);
  EPI_VARS
  f32x4 acc[8][4];
  ZERO8x4(acc)
  gemm256(P + ((size_t)pc << 20) + (size_t)ti * 256 * 1024, 1024,
          Vt + (p << 20) + (size_t)dj * 256 * 1024, 1024, (ti + 1) * 4, acc, lds);
  int b = (int)(p >> 1), h = (int)(p & 1);
#pragma unroll
  for (int mi = 0; mi < 8; ++mi)
#pragma unroll
    for (int ni = 0; ni < 4; ++ni) {
      int dcol = dj * 256 + wc * 64 + ni * 16 + fr;
      f32x4 a = acc[mi][ni];
#pragma unroll
      for (int r = 0; r < 4; ++r) {
        int tk = ti * 256 + wr * 128 + mi * 16 + fq * 4 + r;
        O[(((size_t)b << 10) + tk) * 2048 + (h << 10) + dcol] = (bf16_t)a[r];
      }
    }
}

// ---------------- GEMM 4: out = O * Wo^T (fp32 out) ----------------
__global__ __launch_bounds__(512, 2) void k_out256(const bf16_t* __restrict__ O,
                                                   const bf16_t* __restrict__ W,
                                                   float* __restrict__ out) {
  __shared__ __align__(16) bf16_t lds[65536];
  int bid = (int)blockIdx.x;
  int id = (bid & 7) * 128 + (bid >> 3);  // XCD swizzle (1024 = 8*128)
  int mt = id & 127, ntile = id >> 7;     // B-panel-major
  EPI_VARS
  f32x4 acc[8][4];
  ZERO8x4(acc)
  gemm256(O + (size_t)mt * 256 * 2048, 2048, W + (size_t)ntile * 256 * 2048, 2048, 32, acc, lds);
#pragma unroll
  for (int mi = 0; mi < 8; ++mi)
#pragma unroll
    for (int ni = 0; ni < 4; ++ni) {
      int col = ntile * 256 + wc * 64 + ni * 16 + fr;
      f32x4 a = acc[mi][ni];
#pragma unroll
      for (int r = 0; r < 4; ++r) {
        int row = mt * 256 + wr * 128 + mi * 16 + fq * 4 + r;
        out[(size_t)row * 2048 + col] = a[r];
      }
    }
}

// ---------------- launch ----------------
extern "C" void kernel_launch(void* const* d_in, const int* in_sizes, int n_in,
                              void* d_out, int out_size, void* d_ws, size_t ws_size,
                              hipStream_t stream) {
  const float* x  = (const float*)d_in[0];
  const float* Wq = (const float*)d_in[1];
  const float* bq = (const float*)d_in[2];
  const float* Wk = (const float*)d_in[3];
  const float* bk = (const float*)d_in[4];
  const float* Wv = (const float*)d_in[5];
  const float* bv = (const float*)d_in[6];
  const float* Wo = (const float*)d_in[7];
  float* out = (float*)d_out;

  const size_t MiB = 1ull << 20;
  char* w = (char*)d_ws;
  bf16_t* xb    = (bf16_t*)w;               // 128 MiB, reused as O after QKV
  bf16_t* Ob    = xb;
  bf16_t* Qb    = (bf16_t*)(w + 128 * MiB); // 128 MiB
  bf16_t* Kb    = (bf16_t*)(w + 256 * MiB); // 128 MiB
  bf16_t* Vt    = (bf16_t*)(w + 384 * MiB); // 128 MiB (transposed V)
  bf16_t* Wqkvb = (bf16_t*)(w + 512 * MiB); // 24 MiB  [Wq;Wk;Wv]
  bf16_t* Wob   = (bf16_t*)(w + 536 * MiB); // 8 MiB
  float*  Sc    = (float*)(w + 544 * MiB);  // NP * 4 MiB

  size_t rem = ws_size > 544 * MiB ? ws_size - 544 * MiB : 0;
  int NP = (int)(rem / (6 * MiB));
  if (NP > 64) NP = 64;
  if (NP < 1) {
    k_fill<<<2048, 256, 0, stream>>>(out, (float)(ws_size >> 20), (long)out_size);
    return;
  }
  bf16_t* Pc = (bf16_t*)(w + 544 * MiB + (size_t)NP * 4 * MiB); // NP * 2 MiB

  // conversions to bf16
  k_cvt<<<2048, 256, 0, stream>>>(x, xb, 8388608L);
  k_cvt<<<1024, 256, 0, stream>>>(Wq, Wqkvb, 524288L);
  k_cvt<<<1024, 256, 0, stream>>>(Wk, Wqkvb + 4194304, 524288L);
  k_cvt<<<1024, 256, 0, stream>>>(Wv, Wqkvb + 8388608, 524288L);
  k_cvt<<<1024, 256, 0, stream>>>(Wo, Wob, 524288L);

  // QKV projection (Q,K normal layout; V transposed)
  k_qkv256<<<3072, 512, 0, stream>>>(xb, Wqkvb, bq, bk, bv, Qb, Kb, Vt);

  // attention, chunked over (b,h) pairs to bound scratch
  for (int base = 0; base < 64; base += NP) {
    int np = (64 - base) < NP ? (64 - base) : NP;
    k_s256<<<np * 10, 512, 0, stream>>>(Qb, Kb, Sc, base);
    k_softmax<<<np * 1024, 256, 0, stream>>>(Sc, Pc);
    k_pv256<<<np * 16, 512, 0, stream>>>(Pc, Vt, Ob, base);
  }

  // output projection
  k_out256<<<1024, 512, 0, stream>>>(Ob, Wob, out);
}